// Round 18
// baseline (235.986 us; speedup 1.0000x reference)
//
#include <hip/hip_runtime.h>
#include <hip/hip_bf16.h>
#include <math.h>

// MultiHeadDiffAttention, MI355X. Round 24: fuse x-cast into gemm_qkv.
// R23 re-verified best (212.9us; session 295->213). attn levers exhausted
// (memory R22-falsified, sync R13, occupancy R12/R21, setprio R17); last
// bounded win: cast_bf16 runs at HBM ceiling (~48MB/8us) -> shrink it.
// gemm_qkv now reads x as f32 directly, converting during A-staging via
// T14 reg-staged split: issue 2x float4 right after barrier (latency under
// MFMA phase), bf16rne-convert, ds_write_b128 to the IDENTICAL swizzled
// LDS slot -> readers/layout unchanged. W-path keeps global_load_lds.
// Traffic net-neutral (save 24MB cast, add 24MB f32 A-reads, L3-absorbed);
// cast halves (grid 2048, weights only). attn v12 unchanged (79.8).
// Predicted: cast ~8->4us, qkv +0-2, pipeline 213 -> ~207-210.
// Null/regress -> restore R23 and declare local optimum.
// B=2 S=2048 E=1024 H=8 DH=128 F=64.
// ws layout (64 MB):
//   [Oacc 32MB f32][wob 2MB][wqb 2MB <- Lacc overlays][wkb 2][wvb 2]
//   [Qb 8MB <- Nb overlays after attn][Kb 8MB][Vtb 8MB]

#define SDIM 2048
#define EDIM 1024
#define HDIM 8
#define DHDIM 128

typedef unsigned short u16;
typedef __attribute__((ext_vector_type(8))) short bf16x8;
typedef __attribute__((ext_vector_type(4))) short bf16x4;
typedef __attribute__((ext_vector_type(4))) u16 u16x4;
typedef __attribute__((ext_vector_type(8))) u16 u16x8;
typedef __attribute__((ext_vector_type(4))) float f32x4;

__device__ __forceinline__ u16 bf16rne(float f) {
    unsigned int u = __float_as_uint(f);
    u += 0x7fff + ((u >> 16) & 1);
    return (u16)(u >> 16);
}

__device__ __forceinline__ void gload16(void* lds, const void* g) {
    __builtin_amdgcn_global_load_lds(
        (const __attribute__((address_space(1))) unsigned int*)g,
        (__attribute__((address_space(3))) unsigned int*)lds, 16, 0, 0);
}

__device__ __forceinline__ u16x8 cvt8(float4 a, float4 b) {
    u16x8 o;
    o[0] = bf16rne(a.x); o[1] = bf16rne(a.y); o[2] = bf16rne(a.z); o[3] = bf16rne(a.w);
    o[4] = bf16rne(b.x); o[5] = bf16rne(b.y); o[6] = bf16rne(b.z); o[7] = bf16rne(b.w);
    return o;
}

constexpr int GM = 4096, GN = 1024, GK = 1024;

// ------------------------------------------------------------------
// cast fp32 -> bf16: weights only now (Wq/Wk/Wv/Wo, 1M each).
// ------------------------------------------------------------------
__global__ __launch_bounds__(256) void cast_bf16(
    const float* __restrict__ wq, const float* __restrict__ wk,
    const float* __restrict__ wv, const float* __restrict__ wo,
    u16* __restrict__ wqb, u16* __restrict__ wkb,
    u16* __restrict__ wvb, u16* __restrict__ wob)
{
    int bid = blockIdx.x;
    const float* src; u16* dst; int lb;
    if (bid < 512)       { src = wq; dst = wqb; lb = bid; }
    else if (bid < 1024) { src = wk; dst = wkb; lb = bid - 512; }
    else if (bid < 1536) { src = wv; dst = wvb; lb = bid - 1024; }
    else                 { src = wo; dst = wob; lb = bid - 1536; }
    size_t i = ((size_t)lb * 256 + threadIdx.x) * 8;
    float4 a = *(const float4*)&src[i];
    float4 b = *(const float4*)&src[i + 4];
    *(u16x8*)&dst[i] = cvt8(a, b);
}

struct GemmCore {
    f32x4 acc[4][4];
    int m0, n0, wm, wn, ln, quad;
};

__device__ __forceinline__ void gemm_swz(GemmCore& g) {
    // T1 XCD swizzle: hw bid -> logical swz so each XCD (bid%8) owns a
    // contiguous chunk of tiles -> W+A L2-fit. Bijective (nwg%8==0).
    const int bid = blockIdx.y * gridDim.x + blockIdx.x;
    const int cpx = (gridDim.x * gridDim.y) >> 3;
    const int swz = (bid & 7) * cpx + (bid >> 3);
    g.m0 = (swz / gridDim.x) * 128;
    g.n0 = (swz % gridDim.x) * 128;
}

// ------------------------------------------------------------------
// GEMM core BK=32, dbuf 1-barrier, qkv path. A read as FP32 with
// inline bf16 conversion (reg-staged: load after barrier, convert +
// ds_write_b128 after compute -> latency hidden under MFMA phase).
// W staged via global_load_lds (bf16). LDS layout identical to R21.
// ------------------------------------------------------------------
#define QBUF 4096

__device__ __forceinline__ void gemm_core32f(
    GemmCore& g, const float* __restrict__ X, const u16* __restrict__ W,
    u16* AsBase, u16* BsBase)
{
    const int tid = threadIdx.x;
    const int lane = tid & 63;
    const int wv = tid >> 6;
    g.ln = lane & 15; g.quad = lane >> 4;
    g.wm = (wv >> 1) * 64; g.wn = (wv & 1) * 64;
    gemm_swz(g);

#pragma unroll
    for (int i = 0; i < 4; ++i)
#pragma unroll
        for (int j = 0; j < 4; ++j)
            g.acc[i][j] = (f32x4){0.f, 0.f, 0.f, 0.f};

    const int s0 = tid, s1 = tid + 256;
    const int ar0 = s0 >> 2, ac0 = (((s0 & 3) ^ ((ar0 >> 1) & 3)) * 8);
    const int ar1 = s1 >> 2, ac1 = (((s1 & 3) ^ ((ar1 >> 1) & 3)) * 8);
    const float* xa0 = X + (size_t)(g.m0 + ar0) * GK + ac0;
    const float* xa1 = X + (size_t)(g.m0 + ar1) * GK + ac1;
    const u16* pb0 = W + (size_t)(g.n0 + ar0) * GK + ac0;
    const u16* pb1 = W + (size_t)(g.n0 + ar1) * GK + ac1;
    u16* la0 = AsBase + s0 * 8; u16* la1 = AsBase + s1 * 8;
    u16* lb0 = BsBase + s0 * 8; u16* lb1 = BsBase + s1 * 8;

    const int roff = ((g.quad ^ ((g.ln >> 1) & 3)) * 8);

    // prologue: stage k0=0 into buffer 0 (A via reg-convert, W via DMA)
    {
        float4 a0 = *(const float4*)(xa0);
        float4 a1 = *(const float4*)(xa0 + 4);
        float4 b0 = *(const float4*)(xa1);
        float4 b1 = *(const float4*)(xa1 + 4);
        *(u16x8*)la0 = cvt8(a0, a1);
        *(u16x8*)la1 = cvt8(b0, b1);
    }
    gload16(lb0, pb0); gload16(lb1, pb1);

    for (int k0 = 0; k0 < GK; k0 += 32) {
        const int cur = (k0 >> 5) & 1;
        __syncthreads();   // buf[cur] staged; all waves done with buf[cur^1]

        const bool pf = (k0 + 32 < GK);
        float4 na0, na1, nb0l, nb1l;
        if (pf) {
            // issue next-iter A loads now (latency hides under compute)
            na0  = *(const float4*)(xa0 + k0 + 32);
            na1  = *(const float4*)(xa0 + k0 + 36);
            nb0l = *(const float4*)(xa1 + k0 + 32);
            nb1l = *(const float4*)(xa1 + k0 + 36);
            const int nb = (cur ^ 1) * QBUF;
            gload16(lb0 + nb, pb0 + k0 + 32); gload16(lb1 + nb, pb1 + k0 + 32);
        }

        const u16* Ac = AsBase + cur * QBUF;
        const u16* Bc = BsBase + cur * QBUF;

        bf16x8 af[4], bfr[4];
#pragma unroll
        for (int t = 0; t < 4; ++t) {
            af[t]  = *(const bf16x8*)&Ac[(g.wm + t * 16 + g.ln) * 32 + roff];
            bfr[t] = *(const bf16x8*)&Bc[(g.wn + t * 16 + g.ln) * 32 + roff];
        }
#pragma unroll
        for (int i = 0; i < 4; ++i)
#pragma unroll
            for (int j = 0; j < 4; ++j)
                g.acc[i][j] = __builtin_amdgcn_mfma_f32_16x16x32_bf16(
                    af[i], bfr[j], g.acc[i][j], 0, 0, 0);

        if (pf) {
            const int nb = (cur ^ 1) * QBUF;
            *(u16x8*)(la0 + nb) = cvt8(na0, na1);
            *(u16x8*)(la1 + nb) = cvt8(nb0l, nb1l);
        }
    }
}

// ------------------------------------------------------------------
// GEMM core BK=64, dbuf 1-barrier (gemm_out path, R20-proven). LDS 64KB.
// ------------------------------------------------------------------
#define GBUF 8192

__device__ __forceinline__ void gemm_core64(
    GemmCore& g, const u16* __restrict__ A, const u16* __restrict__ W,
    u16* AsBase, u16* BsBase)
{
    const int tid = threadIdx.x;
    const int lane = tid & 63;
    const int wv = tid >> 6;
    g.ln = lane & 15; g.quad = lane >> 4;
    g.wm = (wv >> 1) * 64; g.wn = (wv & 1) * 64;
    gemm_swz(g);

#pragma unroll
    for (int i = 0; i < 4; ++i)
#pragma unroll
        for (int j = 0; j < 4; ++j)
            g.acc[i][j] = (f32x4){0.f, 0.f, 0.f, 0.f};

    const int s0 = tid, s1 = tid + 256, s2 = tid + 512, s3 = tid + 768;
    const int ar0 = s0 >> 3, ac0 = ((s0 & 7) ^ (ar0 & 7)) * 8;
    const int ar1 = s1 >> 3, ac1 = ((s1 & 7) ^ (ar1 & 7)) * 8;
    const int ar2 = s2 >> 3, ac2 = ((s2 & 7) ^ (ar2 & 7)) * 8;
    const int ar3 = s3 >> 3, ac3 = ((s3 & 7) ^ (ar3 & 7)) * 8;
    const u16* pa0 = A + (size_t)(g.m0 + ar0) * GK + ac0;
    const u16* pa1 = A + (size_t)(g.m0 + ar1) * GK + ac1;
    const u16* pa2 = A + (size_t)(g.m0 + ar2) * GK + ac2;
    const u16* pa3 = A + (size_t)(g.m0 + ar3) * GK + ac3;
    const u16* pb0 = W + (size_t)(g.n0 + ar0) * GK + ac0;
    const u16* pb1 = W + (size_t)(g.n0 + ar1) * GK + ac1;
    const u16* pb2 = W + (size_t)(g.n0 + ar2) * GK + ac2;
    const u16* pb3 = W + (size_t)(g.n0 + ar3) * GK + ac3;
    u16* la0 = AsBase + s0 * 8; u16* la1 = AsBase + s1 * 8;
    u16* la2 = AsBase + s2 * 8; u16* la3 = AsBase + s3 * 8;
    u16* lb0 = BsBase + s0 * 8; u16* lb1 = BsBase + s1 * 8;
    u16* lb2 = BsBase + s2 * 8; u16* lb3 = BsBase + s3 * 8;

    // prologue: stage k0=0 into buffer 0
    gload16(la0, pa0); gload16(la1, pa1);
    gload16(la2, pa2); gload16(la3, pa3);
    gload16(lb0, pb0); gload16(lb1, pb1);
    gload16(lb2, pb2); gload16(lb3, pb3);

    for (int k0 = 0; k0 < GK; k0 += 64) {
        const int cur = (k0 >> 6) & 1;
        __syncthreads();

        if (k0 + 64 < GK) {
            const int nb = (cur ^ 1) * GBUF;
            gload16(la0 + nb, pa0 + k0 + 64); gload16(la1 + nb, pa1 + k0 + 64);
            gload16(la2 + nb, pa2 + k0 + 64); gload16(la3 + nb, pa3 + k0 + 64);
            gload16(lb0 + nb, pb0 + k0 + 64); gload16(lb1 + nb, pb1 + k0 + 64);
            gload16(lb2 + nb, pb2 + k0 + 64); gload16(lb3 + nb, pb3 + k0 + 64);
        }

        const u16* Ac = AsBase + cur * GBUF;
        const u16* Bc = BsBase + cur * GBUF;

        bf16x8 af[4][2], bfr[4][2];
#pragma unroll
        for (int t = 0; t < 4; ++t) {
#pragma unroll
            for (int kk = 0; kk < 2; ++kk) {
                const int ra = g.wm + t * 16 + g.ln;
                const int rb = g.wn + t * 16 + g.ln;
                af[t][kk]  = *(const bf16x8*)&Ac[ra * 64 + (((kk * 4 + g.quad) ^ (ra & 7)) * 8)];
                bfr[t][kk] = *(const bf16x8*)&Bc[rb * 64 + (((kk * 4 + g.quad) ^ (rb & 7)) * 8)];
            }
        }
#pragma unroll
        for (int i = 0; i < 4; ++i)
#pragma unroll
            for (int j = 0; j < 4; ++j)
#pragma unroll
                for (int kk = 0; kk < 2; ++kk)
                    g.acc[i][j] = __builtin_amdgcn_mfma_f32_16x16x32_bf16(
                        af[i][kk], bfr[j][kk], g.acc[i][j], 0, 0, 0);
    }
}

// z=0 -> Qb (bf16, PRE-SCALED by 0.125*log2e), z=1 -> Kb, z=2 -> Vt.
// z=2 uses LDS-staged transpose for coalesced Vt stores (256B rows).
#define TSTR 136   // transpose-row stride in u16: 272B, 16B-aligned

__global__ __launch_bounds__(256) void gemm_qkv(
    const float* __restrict__ X,
    const u16* __restrict__ W0, const u16* __restrict__ W1, const u16* __restrict__ W2,
    u16* __restrict__ Qb, u16* __restrict__ Kb, u16* __restrict__ Vtb)
{
    __shared__ u16 Sh[17408];
    const int z = blockIdx.z;
    const u16* W = (z == 0) ? W0 : ((z == 1) ? W1 : W2);
    GemmCore g;
    gemm_core32f(g, X, W, Sh, Sh + 2 * QBUF);

    if (z < 2) {
        const float scl = (z == 0) ? 0.125f * 1.44269504f : 1.0f;
        u16* C = (z == 0) ? Qb : Kb;
#pragma unroll
        for (int i = 0; i < 4; ++i) {
            int rb = g.m0 + g.wm + i * 16 + g.quad * 4;
#pragma unroll
            for (int r = 0; r < 4; ++r) {
                u16* crow = C + (size_t)(rb + r) * GN + g.n0 + g.wn + g.ln;
#pragma unroll
                for (int j = 0; j < 4; ++j)
                    crow[j * 16] = bf16rne(g.acc[i][j][r] * scl);
            }
        }
    } else {
        // ---- LDS-staged transpose: Ts[n_local][m_local], stride TSTR ----
        __syncthreads();   // all waves done with staging LDS
        u16* Ts = Sh;      // 128*136 = 17408 u16
#pragma unroll
        for (int i = 0; i < 4; ++i)
#pragma unroll
            for (int j = 0; j < 4; ++j) {
                const int nl = g.wn + j * 16 + g.ln;
                const int ml = g.wm + i * 16 + g.quad * 4;
                u16x4 pk;
#pragma unroll
                for (int r = 0; r < 4; ++r) pk[r] = bf16rne(g.acc[i][j][r]);
                *(u16x4*)&Ts[nl * TSTR + ml] = pk;
            }
        __syncthreads();

        // ---- coalesced stores: each Vt row = 256B contiguous ----
        const int tid = threadIdx.x;
        const int c = tid & 15;
        const int bb = g.m0 >> 11;
        const int sb0 = g.m0 & 2047;
        const int hh = g.n0 >> 7;
#pragma unroll
        for (int s = 0; s < 8; ++s) {
            const int rown = (tid >> 4) + s * 16;          // n_local 0..127
            u16x8 v = *(const u16x8*)&Ts[rown * TSTR + c * 8];
            u16* vrow = Vtb + (((size_t)bb * 8 + hh) * DHDIM + rown) * SDIM + sb0;
            *(u16x8*)&vrow[c * 8] = v;
        }
    }
}

// out = (A @ W.T + bias) * (1-dw), fp32 output (BK=64 dbuf core)
__global__ __launch_bounds__(256) void gemm_out(
    const u16* __restrict__ A, const u16* __restrict__ W,
    float* __restrict__ C, const float* __restrict__ bias,
    const float* __restrict__ dwp)
{
    __shared__ u16 Sh[4 * GBUF];
    GemmCore g;
    gemm_core64(g, A, W, Sh, Sh + 2 * GBUF);

    const float scale = 1.0f - dwp[0];
    float bv[4];
#pragma unroll
    for (int j = 0; j < 4; ++j) bv[j] = bias[g.n0 + g.wn + j * 16 + g.ln];
#pragma unroll
    for (int i = 0; i < 4; ++i) {
        int rb = g.m0 + g.wm + i * 16 + g.quad * 4;
#pragma unroll
        for (int r = 0; r < 4; ++r) {
            float* crow = C + (size_t)(rb + r) * GN + g.n0 + g.wn + g.ln;
#pragma unroll
            for (int j = 0; j < 4; ++j)
                crow[j * 16] = (g.acc[i][j][r] + bv[j]) * scale;
        }
    }
}

// ------------------------------------------------------------------
// MFMA diff attention v12 (R16/R18 body, unchanged, 79.8us):
// branch-split, full-kv/block, KVBLK=64, register-batched K/V frags.
// Block = 4 waves; wave owns 32 q (2 q-tiles) for ONE branch.
// Grid (16 qt, 16 bh, 2 br) = 512 blocks = 2/CU, zero tail.
// ------------------------------------------------------------------
#define KBUF 4096   // u16 per K buffer (64 rows x 64 feats)
#define VBUF 8192   // u16 per V buffer (2 subs x 128 dh x 32 kv)

__global__ __launch_bounds__(256, 2) void attn_mfma(
    const u16* __restrict__ Qb, const u16* __restrict__ Kb,
    const u16* __restrict__ Vtb,
    float* __restrict__ Oacc, float* __restrict__ Lacc)
{
    __shared__ u16 Ks[2 * KBUF];
    __shared__ u16 Vs[2 * VBUF];

    const int tid = threadIdx.x;
    const int wv   = tid >> 6;
    const int lane = tid & 63;
    const int ln = lane & 15, quad = lane >> 4;
    const int lx = ln & 7;
    const int vkey = (ln >> 1) & 3;
    const int bh = blockIdx.y, b = bh >> 3, h = bh & 7;
    const int q0 = blockIdx.x * 128 + wv * 32;        // wave's 32 q rows
    const int BR = blockIdx.z;                        // branch 0/1

    // Q B-frags (pre-scaled): [qt][half], branch BR feats BR*64 + half*32 + quad*8
    const size_t qoff = (size_t)b * SDIM * EDIM + h * DHDIM + BR * 64;
    bf16x8 aq[2][2];
#pragma unroll
    for (int qt = 0; qt < 2; ++qt) {
        const u16* qp = Qb + qoff + (size_t)(q0 + qt * 16 + ln) * EDIM + quad * 8;
        aq[qt][0] = *(const bf16x8*)(qp);
        aq[qt][1] = *(const bf16x8*)(qp + 32);
    }

    // staging maps.
    // K: slot s (16B) -> row s>>3 (0..63), chunk ((s&7)^(row&7)) of 8.
    // V per 32-kv sub: slot s -> row s>>2 (0..127), chunk ((s&3)^((row>>1)&3)).
    const int s0 = tid, s1 = tid + 256;
    const int kr0 = s0 >> 3, kc0 = ((s0 & 7) ^ (kr0 & 7)) * 8;
    const int kr1 = s1 >> 3, kc1 = ((s1 & 7) ^ (kr1 & 7)) * 8;
    const u16* kg0 = Kb + (size_t)(b * SDIM + kr0) * EDIM + h * DHDIM + BR * 64 + kc0;
    const u16* kg1 = Kb + (size_t)(b * SDIM + kr1) * EDIM + h * DHDIM + BR * 64 + kc1;
    const int vr0 = s0 >> 2, vc0 = ((s0 & 3) ^ ((vr0 >> 1) & 3)) * 8;
    const int vr1 = s1 >> 2, vc1 = ((s1 & 3) ^ ((vr1 >> 1) & 3)) * 8;
    const u16* vg0 = Vtb + ((size_t)bh * DHDIM + vr0) * SDIM + vc0;
    const u16* vg1 = Vtb + ((size_t)bh * DHDIM + vr1) * SDIM + vc1;
    u16* ksd0 = Ks + s0 * 8; u16* ksd1 = Ks + s1 * 8;
    u16* vsd0 = Vs + s0 * 8; u16* vsd1 = Vs + s1 * 8;

    // prologue: stage iter 0 into buffer 0 (kv 0..63)
    gload16(ksd0, kg0); gload16(ksd1, kg1);
    gload16(vsd0, vg0); gload16(vsd1, vg1);
    gload16(vsd0 + 4096, vg0 + 32); gload16(vsd1 + 4096, vg1 + 32);
    kg0 += 64 * EDIM; kg1 += 64 * EDIM; vg0 += 64; vg1 += 64;

    f32x4 acc[2][8];                    // [qt][dt], one branch
#pragma unroll
    for (int qt = 0; qt < 2; ++qt)
#pragma unroll
        for (int d = 0; d < 8; ++d)
            acc[qt][d] = (f32x4){0.f, 0.f, 0.f, 0.f};
    float lsum[2] = {0.f, 0.f};
    const f32x4 z4 = (f32x4){0.f, 0.f, 0.f, 0.f};

    for (int it = 0; it < 32; ++it) {
        const int cur = it & 1;
        __syncthreads();   // buf[cur] loads complete; all waves done with buf[cur^1]

        if (it < 31) {     // prefetch iter it+1 into the other buffer
            const int kb = (cur ^ 1) * KBUF, vb2 = (cur ^ 1) * VBUF;
            gload16(ksd0 + kb, kg0); gload16(ksd1 + kb, kg1);
            gload16(vsd0 + vb2, vg0); gload16(vsd1 + vb2, vg1);
            gload16(vsd0 + vb2 + 4096, vg0 + 32); gload16(vsd1 + vb2 + 4096, vg1 + 32);
            kg0 += 64 * EDIM; kg1 += 64 * EDIM; vg0 += 64; vg1 += 64;
        }

        const u16* Kc = Ks + cur * KBUF;
        const u16* Vc = Vs + cur * VBUF;

        // ---- batch-load ALL K frags for this iter (8 x ds_read_b128) ----
        bf16x8 kf[4][2];
#pragma unroll
        for (int t2 = 0; t2 < 4; ++t2) {
            const int rb = (t2 * 16 + ln) * 64;
            kf[t2][0] = *(const bf16x8*)&Kc[rb + ((quad ^ lx) * 8)];
            kf[t2][1] = *(const bf16x8*)&Kc[rb + (((4 + quad) ^ lx) * 8)];
        }

        // ---- S^T over 64 kv: st[qt][t2] (MFMAs back-to-back) ----
        f32x4 st[2][4];
#pragma unroll
        for (int t2 = 0; t2 < 4; ++t2)
#pragma unroll
            for (int qt = 0; qt < 2; ++qt) {
                f32x4 s = __builtin_amdgcn_mfma_f32_16x16x32_bf16(kf[t2][0], aq[qt][0], z4, 0, 0, 0);
                st[qt][t2] = __builtin_amdgcn_mfma_f32_16x16x32_bf16(kf[t2][1], aq[qt][1], s, 0, 0, 0);
            }

        // ---- batch-load ALL V frags for this iter (32 x ds_read_b64) ----
        bf16x8 vf[8][2];
#pragma unroll
        for (int dt = 0; dt < 8; ++dt) {
            const int vb = (dt * 16 + ln) * 32;
#pragma unroll
            for (int ks = 0; ks < 2; ++ks) {
                const u16* Vk = Vc + ks * 4096;
                bf16x4 vlo = *(const bf16x4*)&Vk[vb + ((((quad >> 1) + 0) ^ vkey) * 8 + (quad & 1) * 4)];
                bf16x4 vhi = *(const bf16x4*)&Vk[vb + ((((quad >> 1) + 2) ^ vkey) * 8 + (quad & 1) * 4)];
                vf[dt][ks] = __builtin_shufflevector(vlo, vhi, 0, 1, 2, 3, 4, 5, 6, 7);
            }
        }

        // ---- exp + lsum + in-register pack: ap[qt][ks] (ks = kv-32-half) ----
        union { unsigned int u[4]; bf16x8 v; } ap[2][2];
#pragma unroll
        for (int qt = 0; qt < 2; ++qt)
#pragma unroll
            for (int ks = 0; ks < 2; ++ks) {
                float e0 = exp2f(st[qt][2 * ks][0]), e1 = exp2f(st[qt][2 * ks][1]);
                float e2 = exp2f(st[qt][2 * ks][2]), e3 = exp2f(st[qt][2 * ks][3]);
                float f0 = exp2f(st[qt][2 * ks + 1][0]), f1 = exp2f(st[qt][2 * ks + 1][1]);
                float f2 = exp2f(st[qt][2 * ks + 1][2]), f3 = exp2f(st[qt][2 * ks + 1][3]);
                lsum[qt] += (e0 + e1) + (e2 + e3) + (f0 + f1) + (f2 + f3);
                ap[qt][ks].u[0] = __builtin_amdgcn_perm(__float_as_uint(e1), __float_as_uint(e0), 0x07060302u);
                ap[qt][ks].u[1] = __builtin_amdgcn_perm(__float_as_uint(e3), __float_as_uint(e2), 0x07060302u);
                ap[qt][ks].u[2] = __builtin_amdgcn_perm(__float_as_uint(f1), __float_as_uint(f0), 0x07060302u);
                ap[qt][ks].u[3] = __builtin_amdgcn_perm(__float_as_uint(f3), __float_as_uint(f2), 0x07060302u);
            }

        // ---- PV: MFMAs back-to-back from registers ----
#pragma unroll
        for (int dt = 0; dt < 8; ++dt)
#pragma unroll
            for (int ks = 0; ks < 2; ++ks)
#pragma unroll
                for (int qt = 0; qt < 2; ++qt)
                    acc[qt][dt] = __builtin_amdgcn_mfma_f32_16x16x32_bf16(ap[qt][ks].v, vf[dt][ks], acc[qt][dt], 0, 0, 0);
    }

    // ---- epilogue: plain stores (sole writer of branch-BR slots) ----
#pragma unroll
    for (int qt = 0; qt < 2; ++qt) {
#pragma unroll
        for (int r = 0; r < 4; ++r) {
            size_t row = (size_t)(b * SDIM + q0 + qt * 16 + quad * 4 + r);
            float* o = Oacc + ((row * 8 + h) * 2 + BR) * 128 + ln;
#pragma unroll
            for (int dt = 0; dt < 8; ++dt)
                o[dt * 16] = acc[qt][dt][r];
        }
    }
    // ---- l: lane owns q=ln within tile; reduce across quads; store ----
#pragma unroll
    for (int qt = 0; qt < 2; ++qt) {
        float l = lsum[qt];
        l += __shfl_xor(l, 16, 64); l += __shfl_xor(l, 32, 64);
        if (quad == 0)
            Lacc[(size_t)((b * 8 + h) * 2 + BR) * SDIM + q0 + qt * 16 + ln] = l;
    }
}

// ------------------------------------------------------------------
// combine branches + RMSNorm -> bf16 normed. Grid 4096 rows x 256 thr.
// ------------------------------------------------------------------
__global__ __launch_bounds__(256) void rms_combine(
    const float* __restrict__ Oacc, const float* __restrict__ Lacc,
    const float* __restrict__ nw, u16* __restrict__ Nb,
    const float* __restrict__ dwp)
{
    const int row = blockIdx.x;
    const int tid = threadIdx.x;
    const int h = tid >> 5, dh0 = (tid & 31) * 4;
    const int b = row >> 11, q = row & 2047;

    size_t ob = ((size_t)row * 8 + h) * 2 * 128;
    f32x4 a0 = *(const f32x4*)&Oacc[ob + dh0];
    f32x4 a1 = *(const f32x4*)&Oacc[ob + 128 + dh0];
    float l0 = Lacc[(size_t)((b * 8 + h) * 2 + 0) * SDIM + q];
    float l1 = Lacc[(size_t)((b * 8 + h) * 2 + 1) * SDIM + q];
    const float dw = dwp[0];
    float inv0 = 1.0f / l0;
    float inv1 = dw / l1;
    float o[4];
#pragma unroll
    for (int k = 0; k < 4; ++k) o[k] = a0[k] * inv0 - a1[k] * inv1;

    float ss = o[0] * o[0] + o[1] * o[1] + o[2] * o[2] + o[3] * o[3];
    ss += __shfl_xor(ss, 1,  64);
    ss += __shfl_xor(ss, 2,  64);
    ss += __shfl_xor(ss, 4,  64);
    ss += __shfl_xor(ss, 8,  64);
    ss += __shfl_xor(ss, 16, 64);
    ss += __shfl_xor(ss, 32, 64);
    __shared__ float red[4];
    if ((tid & 63) == 0) red[tid >> 6] = ss;
    __syncthreads();
    float tot = red[0] + red[1] + red[2] + red[3];
    float rms = rsqrtf(tot * (1.0f / 1024.0f) + 1.1920929e-07f);

    float4 w = *(const float4*)&nw[tid * 4];
    u16x4 pk;
    pk[0] = bf16rne(o[0] * rms * w.x);
    pk[1] = bf16rne(o[1] * rms * w.y);
    pk[2] = bf16rne(o[2] * rms * w.z);
    pk[3] = bf16rne(o[3] * rms * w.w);
    *(u16x4*)&Nb[(size_t)row * EDIM + tid * 4] = pk;
}

// ------------------------------------------------------------------
extern "C" void kernel_launch(void* const* d_in, const int* in_sizes, int n_in,
                              void* d_out, int out_size, void* d_ws, size_t ws_size,
                              hipStream_t stream)
{
    const float* x   = (const float*)d_in[0];
    const float* Wq  = (const float*)d_in[1];
    const float* Wk  = (const float*)d_in[2];
    const float* Wv  = (const float*)d_in[3];
    const float* nw  = (const float*)d_in[4];
    const float* Wo  = (const float*)d_in[5];
    const float* bo  = (const float*)d_in[6];
    const float* dwp = (const float*)d_in[7];
    float* out = (float*)d_out;

    float* Oacc = (float*)d_ws;                          // 32 MB
    u16*  wob  = (u16*)((char*)d_ws + 33554432);         // 2 MB
    u16*  wqb  = wob + 1048576;
    u16*  wkb  = wqb + 1048576;
    u16*  wvb  = wkb + 1048576;
    float* Lacc = (float*)wqb;                           // overlays wqb (dead)
    u16*  Qb   = wvb + 1048576;                          // 8 MB
    u16*  Kb   = Qb + 4194304;
    u16*  Vtb  = Kb + 4194304;
    u16*  Nb   = Qb;                                     // overlays Qb (dead)

    cast_bf16<<<2048, 256, 0, stream>>>(Wq, Wk, Wv, Wo,
                                        wqb, wkb, wvb, wob);
    gemm_qkv<<<dim3(GN / 128, GM / 128, 3), 256, 0, stream>>>(
        x, wqb, wkb, wvb, Qb, Kb, Vtb);
    attn_mfma<<<dim3(SDIM / 128, 2 * HDIM, 2), 256, 0, stream>>>(
        Qb, Kb, Vtb, Oacc, Lacc);
    rms_combine<<<4096, 256, 0, stream>>>(Oacc, Lacc, nw, Nb, dwp);
    gemm_out<<<dim3(GN / 128, GM / 128, 1), 256, 0, stream>>>(
        Nb, wob, out, bo, dwp);
}

// Round 19
// 212.631 us; speedup vs baseline: 1.1098x; 1.1098x over previous
//
#include <hip/hip_runtime.h>
#include <hip/hip_bf16.h>
#include <math.h>

// MultiHeadDiffAttention, MI355X. Round 25: FINAL -- restore R23 (session
// best, harness-verified twice: 213.15 / 212.89us; session 295 -> 213).
// R24 post-mortem: cast-fusion regressed 213->236. The reg-staged f32
// A-path (load+cvt8+ds_write per thread) put 32 serial chains on qkv's
// critical path -- global_load_lds DMA exists precisely to avoid that
// round-trip. The ~4us cast saving was swamped 6x. Reverted.
// Session ledger: wins = barrier/tail elim + store epilogue (R14, -25%),
// reg-batched LDS reads (R15, -12%), BK=64 drains (R17), dbuf GEMM (R19),
// V^T transpose + GEMM XCD swizzle (R20). Falsified: attn memory latency
// (R22: FETCH 5.6x down, dur UP), sync depth (R13), occupancy (R12/R21),
// setprio (R17), cast fusion (R24). Remaining levers are multi-round
// co-designed rewrites (8-phase pipeline) -- out of single-change scope.
// B=2 S=2048 E=1024 H=8 DH=128 F=64.
// ws layout (64 MB):
//   [Oacc 32MB f32 (xb bf16 overlays head; attn fully overwrites by STORE)]
//   [wob 2MB][wqb 2MB <- Lacc overlays after gemm_qkv][wkb 2][wvb 2]
//   [Qb 8MB <- Nb overlays after attn][Kb 8MB][Vtb 8MB]

#define SDIM 2048
#define EDIM 1024
#define HDIM 8
#define DHDIM 128

typedef unsigned short u16;
typedef __attribute__((ext_vector_type(8))) short bf16x8;
typedef __attribute__((ext_vector_type(4))) short bf16x4;
typedef __attribute__((ext_vector_type(4))) u16 u16x4;
typedef __attribute__((ext_vector_type(8))) u16 u16x8;
typedef __attribute__((ext_vector_type(4))) float f32x4;

__device__ __forceinline__ u16 bf16rne(float f) {
    unsigned int u = __float_as_uint(f);
    u += 0x7fff + ((u >> 16) & 1);
    return (u16)(u >> 16);
}

__device__ __forceinline__ void gload16(void* lds, const void* g) {
    __builtin_amdgcn_global_load_lds(
        (const __attribute__((address_space(1))) unsigned int*)g,
        (__attribute__((address_space(3))) unsigned int*)lds, 16, 0, 0);
}

constexpr int GM = 4096, GN = 1024, GK = 1024;

// ------------------------------------------------------------------
// cast fp32 -> bf16: x (4M) + Wq/Wk/Wv/Wo (1M each).
// ------------------------------------------------------------------
__global__ __launch_bounds__(256) void cast_bf16(
    const float* __restrict__ x,  const float* __restrict__ wq,
    const float* __restrict__ wk, const float* __restrict__ wv,
    const float* __restrict__ wo,
    u16* __restrict__ xb,  u16* __restrict__ wqb, u16* __restrict__ wkb,
    u16* __restrict__ wvb, u16* __restrict__ wob)
{
    int bid = blockIdx.x;
    const float* src; u16* dst; int lb;
    if (bid < 2048)      { src = x;  dst = xb;  lb = bid; }
    else if (bid < 2560) { src = wq; dst = wqb; lb = bid - 2048; }
    else if (bid < 3072) { src = wk; dst = wkb; lb = bid - 2560; }
    else if (bid < 3584) { src = wv; dst = wvb; lb = bid - 3072; }
    else                 { src = wo; dst = wob; lb = bid - 3584; }
    size_t i = ((size_t)lb * 256 + threadIdx.x) * 8;
    float4 a = *(const float4*)&src[i];
    float4 b = *(const float4*)&src[i + 4];
    u16x8 o;
    o[0] = bf16rne(a.x); o[1] = bf16rne(a.y); o[2] = bf16rne(a.z); o[3] = bf16rne(a.w);
    o[4] = bf16rne(b.x); o[5] = bf16rne(b.y); o[6] = bf16rne(b.z); o[7] = bf16rne(b.w);
    *(u16x8*)&dst[i] = o;
}

struct GemmCore {
    f32x4 acc[4][4];
    int m0, n0, wm, wn, ln, quad;
};

__device__ __forceinline__ void gemm_swz(GemmCore& g) {
    // T1 XCD swizzle: hw bid -> logical swz so each XCD (bid%8) owns a
    // contiguous chunk of tiles -> W+A L2-fit. Bijective (nwg%8==0).
    const int bid = blockIdx.y * gridDim.x + blockIdx.x;
    const int cpx = (gridDim.x * gridDim.y) >> 3;
    const int swz = (bid & 7) * cpx + (bid >> 3);
    g.m0 = (swz / gridDim.x) * 128;
    g.n0 = (swz % gridDim.x) * 128;
}

// ------------------------------------------------------------------
// GEMM core BK=32, dbuf 1-barrier (qkv path). LDS 2x2x4096 u16.
// ------------------------------------------------------------------
#define QBUF 4096

__device__ __forceinline__ void gemm_core32(
    GemmCore& g, const u16* __restrict__ A, const u16* __restrict__ W,
    u16* AsBase, u16* BsBase)
{
    const int tid = threadIdx.x;
    const int lane = tid & 63;
    const int wv = tid >> 6;
    g.ln = lane & 15; g.quad = lane >> 4;
    g.wm = (wv >> 1) * 64; g.wn = (wv & 1) * 64;
    gemm_swz(g);

#pragma unroll
    for (int i = 0; i < 4; ++i)
#pragma unroll
        for (int j = 0; j < 4; ++j)
            g.acc[i][j] = (f32x4){0.f, 0.f, 0.f, 0.f};

    const int s0 = tid, s1 = tid + 256;
    const int ar0 = s0 >> 2, ac0 = (((s0 & 3) ^ ((ar0 >> 1) & 3)) * 8);
    const int ar1 = s1 >> 2, ac1 = (((s1 & 3) ^ ((ar1 >> 1) & 3)) * 8);
    const u16* pa0 = A + (size_t)(g.m0 + ar0) * GK + ac0;
    const u16* pa1 = A + (size_t)(g.m0 + ar1) * GK + ac1;
    const u16* pb0 = W + (size_t)(g.n0 + ar0) * GK + ac0;
    const u16* pb1 = W + (size_t)(g.n0 + ar1) * GK + ac1;
    u16* la0 = AsBase + s0 * 8; u16* la1 = AsBase + s1 * 8;
    u16* lb0 = BsBase + s0 * 8; u16* lb1 = BsBase + s1 * 8;

    const int roff = ((g.quad ^ ((g.ln >> 1) & 3)) * 8);

    // prologue: stage k0=0 into buffer 0
    gload16(la0, pa0); gload16(la1, pa1);
    gload16(lb0, pb0); gload16(lb1, pb1);

    for (int k0 = 0; k0 < GK; k0 += 32) {
        const int cur = (k0 >> 5) & 1;
        __syncthreads();   // buf[cur] staged; all waves done with buf[cur^1]

        if (k0 + 32 < GK) {
            const int nb = (cur ^ 1) * QBUF;
            gload16(la0 + nb, pa0 + k0 + 32); gload16(la1 + nb, pa1 + k0 + 32);
            gload16(lb0 + nb, pb0 + k0 + 32); gload16(lb1 + nb, pb1 + k0 + 32);
        }

        const u16* Ac = AsBase + cur * QBUF;
        const u16* Bc = BsBase + cur * QBUF;

        bf16x8 af[4], bfr[4];
#pragma unroll
        for (int t = 0; t < 4; ++t) {
            af[t]  = *(const bf16x8*)&Ac[(g.wm + t * 16 + g.ln) * 32 + roff];
            bfr[t] = *(const bf16x8*)&Bc[(g.wn + t * 16 + g.ln) * 32 + roff];
        }
#pragma unroll
        for (int i = 0; i < 4; ++i)
#pragma unroll
            for (int j = 0; j < 4; ++j)
                g.acc[i][j] = __builtin_amdgcn_mfma_f32_16x16x32_bf16(
                    af[i], bfr[j], g.acc[i][j], 0, 0, 0);
    }
}

// ------------------------------------------------------------------
// GEMM core BK=64, dbuf 1-barrier (gemm_out path, R20-proven). LDS 64KB.
// ------------------------------------------------------------------
#define GBUF 8192

__device__ __forceinline__ void gemm_core64(
    GemmCore& g, const u16* __restrict__ A, const u16* __restrict__ W,
    u16* AsBase, u16* BsBase)
{
    const int tid = threadIdx.x;
    const int lane = tid & 63;
    const int wv = tid >> 6;
    g.ln = lane & 15; g.quad = lane >> 4;
    g.wm = (wv >> 1) * 64; g.wn = (wv & 1) * 64;
    gemm_swz(g);

#pragma unroll
    for (int i = 0; i < 4; ++i)
#pragma unroll
        for (int j = 0; j < 4; ++j)
            g.acc[i][j] = (f32x4){0.f, 0.f, 0.f, 0.f};

    const int s0 = tid, s1 = tid + 256, s2 = tid + 512, s3 = tid + 768;
    const int ar0 = s0 >> 3, ac0 = ((s0 & 7) ^ (ar0 & 7)) * 8;
    const int ar1 = s1 >> 3, ac1 = ((s1 & 7) ^ (ar1 & 7)) * 8;
    const int ar2 = s2 >> 3, ac2 = ((s2 & 7) ^ (ar2 & 7)) * 8;
    const int ar3 = s3 >> 3, ac3 = ((s3 & 7) ^ (ar3 & 7)) * 8;
    const u16* pa0 = A + (size_t)(g.m0 + ar0) * GK + ac0;
    const u16* pa1 = A + (size_t)(g.m0 + ar1) * GK + ac1;
    const u16* pa2 = A + (size_t)(g.m0 + ar2) * GK + ac2;
    const u16* pa3 = A + (size_t)(g.m0 + ar3) * GK + ac3;
    const u16* pb0 = W + (size_t)(g.n0 + ar0) * GK + ac0;
    const u16* pb1 = W + (size_t)(g.n0 + ar1) * GK + ac1;
    const u16* pb2 = W + (size_t)(g.n0 + ar2) * GK + ac2;
    const u16* pb3 = W + (size_t)(g.n0 + ar3) * GK + ac3;
    u16* la0 = AsBase + s0 * 8; u16* la1 = AsBase + s1 * 8;
    u16* la2 = AsBase + s2 * 8; u16* la3 = AsBase + s3 * 8;
    u16* lb0 = BsBase + s0 * 8; u16* lb1 = BsBase + s1 * 8;
    u16* lb2 = BsBase + s2 * 8; u16* lb3 = BsBase + s3 * 8;

    // prologue: stage k0=0 into buffer 0
    gload16(la0, pa0); gload16(la1, pa1);
    gload16(la2, pa2); gload16(la3, pa3);
    gload16(lb0, pb0); gload16(lb1, pb1);
    gload16(lb2, pb2); gload16(lb3, pb3);

    for (int k0 = 0; k0 < GK; k0 += 64) {
        const int cur = (k0 >> 6) & 1;
        __syncthreads();

        if (k0 + 64 < GK) {
            const int nb = (cur ^ 1) * GBUF;
            gload16(la0 + nb, pa0 + k0 + 64); gload16(la1 + nb, pa1 + k0 + 64);
            gload16(la2 + nb, pa2 + k0 + 64); gload16(la3 + nb, pa3 + k0 + 64);
            gload16(lb0 + nb, pb0 + k0 + 64); gload16(lb1 + nb, pb1 + k0 + 64);
            gload16(lb2 + nb, pb2 + k0 + 64); gload16(lb3 + nb, pb3 + k0 + 64);
        }

        const u16* Ac = AsBase + cur * GBUF;
        const u16* Bc = BsBase + cur * GBUF;

        bf16x8 af[4][2], bfr[4][2];
#pragma unroll
        for (int t = 0; t < 4; ++t) {
#pragma unroll
            for (int kk = 0; kk < 2; ++kk) {
                const int ra = g.wm + t * 16 + g.ln;
                const int rb = g.wn + t * 16 + g.ln;
                af[t][kk]  = *(const bf16x8*)&Ac[ra * 64 + (((kk * 4 + g.quad) ^ (ra & 7)) * 8)];
                bfr[t][kk] = *(const bf16x8*)&Bc[rb * 64 + (((kk * 4 + g.quad) ^ (rb & 7)) * 8)];
            }
        }
#pragma unroll
        for (int i = 0; i < 4; ++i)
#pragma unroll
            for (int j = 0; j < 4; ++j)
#pragma unroll
                for (int kk = 0; kk < 2; ++kk)
                    g.acc[i][j] = __builtin_amdgcn_mfma_f32_16x16x32_bf16(
                        af[i][kk], bfr[j][kk], g.acc[i][j], 0, 0, 0);
    }
}

// z=0 -> Qb (bf16, PRE-SCALED by 0.125*log2e), z=1 -> Kb, z=2 -> Vt.
// z=2 uses LDS-staged transpose for coalesced Vt stores (256B rows).
#define TSTR 136   // transpose-row stride in u16: 272B, 16B-aligned

__global__ __launch_bounds__(256) void gemm_qkv(
    const u16* __restrict__ A,
    const u16* __restrict__ W0, const u16* __restrict__ W1, const u16* __restrict__ W2,
    u16* __restrict__ Qb, u16* __restrict__ Kb, u16* __restrict__ Vtb)
{
    __shared__ u16 Sh[17408];
    const int z = blockIdx.z;
    const u16* W = (z == 0) ? W0 : ((z == 1) ? W1 : W2);
    GemmCore g;
    gemm_core32(g, A, W, Sh, Sh + 2 * QBUF);

    if (z < 2) {
        const float scl = (z == 0) ? 0.125f * 1.44269504f : 1.0f;
        u16* C = (z == 0) ? Qb : Kb;
#pragma unroll
        for (int i = 0; i < 4; ++i) {
            int rb = g.m0 + g.wm + i * 16 + g.quad * 4;
#pragma unroll
            for (int r = 0; r < 4; ++r) {
                u16* crow = C + (size_t)(rb + r) * GN + g.n0 + g.wn + g.ln;
#pragma unroll
                for (int j = 0; j < 4; ++j)
                    crow[j * 16] = bf16rne(g.acc[i][j][r] * scl);
            }
        }
    } else {
        // ---- LDS-staged transpose: Ts[n_local][m_local], stride TSTR ----
        __syncthreads();   // all waves done with staging LDS
        u16* Ts = Sh;      // 128*136 = 17408 u16
#pragma unroll
        for (int i = 0; i < 4; ++i)
#pragma unroll
            for (int j = 0; j < 4; ++j) {
                const int nl = g.wn + j * 16 + g.ln;
                const int ml = g.wm + i * 16 + g.quad * 4;
                u16x4 pk;
#pragma unroll
                for (int r = 0; r < 4; ++r) pk[r] = bf16rne(g.acc[i][j][r]);
                *(u16x4*)&Ts[nl * TSTR + ml] = pk;
            }
        __syncthreads();

        // ---- coalesced stores: each Vt row = 256B contiguous ----
        const int tid = threadIdx.x;
        const int c = tid & 15;
        const int bb = g.m0 >> 11;
        const int sb0 = g.m0 & 2047;
        const int hh = g.n0 >> 7;
#pragma unroll
        for (int s = 0; s < 8; ++s) {
            const int rown = (tid >> 4) + s * 16;          // n_local 0..127
            u16x8 v = *(const u16x8*)&Ts[rown * TSTR + c * 8];
            u16* vrow = Vtb + (((size_t)bb * 8 + hh) * DHDIM + rown) * SDIM + sb0;
            *(u16x8*)&vrow[c * 8] = v;
        }
    }
}

// out = (A @ W.T + bias) * (1-dw), fp32 output (BK=64 dbuf core)
__global__ __launch_bounds__(256) void gemm_out(
    const u16* __restrict__ A, const u16* __restrict__ W,
    float* __restrict__ C, const float* __restrict__ bias,
    const float* __restrict__ dwp)
{
    __shared__ u16 Sh[4 * GBUF];
    GemmCore g;
    gemm_core64(g, A, W, Sh, Sh + 2 * GBUF);

    const float scale = 1.0f - dwp[0];
    float bv[4];
#pragma unroll
    for (int j = 0; j < 4; ++j) bv[j] = bias[g.n0 + g.wn + j * 16 + g.ln];
#pragma unroll
    for (int i = 0; i < 4; ++i) {
        int rb = g.m0 + g.wm + i * 16 + g.quad * 4;
#pragma unroll
        for (int r = 0; r < 4; ++r) {
            float* crow = C + (size_t)(rb + r) * GN + g.n0 + g.wn + g.ln;
#pragma unroll
            for (int j = 0; j < 4; ++j)
                crow[j * 16] = (g.acc[i][j][r] + bv[j]) * scale;
        }
    }
}

// ------------------------------------------------------------------
// MFMA diff attention v12 (R16/R18 body, unchanged, 79.8us):
// branch-split, full-kv/block, KVBLK=64, register-batched K/V frags.
// Block = 4 waves; wave owns 32 q (2 q-tiles) for ONE branch.
// Grid (16 qt, 16 bh, 2 br) = 512 blocks = 2/CU, zero tail.
// ------------------------------------------------------------------
#define KBUF 4096   // u16 per K buffer (64 rows x 64 feats)
#define VBUF 8192   // u16 per V buffer (2 subs x 128 dh x 32 kv)

__global__ __launch_bounds__(256, 2) void attn_mfma(
    const u16* __restrict__ Qb, const u16* __restrict__ Kb,
    const u16* __restrict__ Vtb,
    float* __restrict__ Oacc, float* __restrict__ Lacc)
{
    __shared__ u16 Ks[2 * KBUF];
    __shared__ u16 Vs[2 * VBUF];

    const int tid = threadIdx.x;
    const int wv   = tid >> 6;
    const int lane = tid & 63;
    const int ln = lane & 15, quad = lane >> 4;
    const int lx = ln & 7;
    const int vkey = (ln >> 1) & 3;
    const int bh = blockIdx.y, b = bh >> 3, h = bh & 7;
    const int q0 = blockIdx.x * 128 + wv * 32;        // wave's 32 q rows
    const int BR = blockIdx.z;                        // branch 0/1

    // Q B-frags (pre-scaled): [qt][half], branch BR feats BR*64 + half*32 + quad*8
    const size_t qoff = (size_t)b * SDIM * EDIM + h * DHDIM + BR * 64;
    bf16x8 aq[2][2];
#pragma unroll
    for (int qt = 0; qt < 2; ++qt) {
        const u16* qp = Qb + qoff + (size_t)(q0 + qt * 16 + ln) * EDIM + quad * 8;
        aq[qt][0] = *(const bf16x8*)(qp);
        aq[qt][1] = *(const bf16x8*)(qp + 32);
    }

    // staging maps.
    // K: slot s (16B) -> row s>>3 (0..63), chunk ((s&7)^(row&7)) of 8.
    // V per 32-kv sub: slot s -> row s>>2 (0..127), chunk ((s&3)^((row>>1)&3)).
    const int s0 = tid, s1 = tid + 256;
    const int kr0 = s0 >> 3, kc0 = ((s0 & 7) ^ (kr0 & 7)) * 8;
    const int kr1 = s1 >> 3, kc1 = ((s1 & 7) ^ (kr1 & 7)) * 8;
    const u16* kg0 = Kb + (size_t)(b * SDIM + kr0) * EDIM + h * DHDIM + BR * 64 + kc0;
    const u16* kg1 = Kb + (size_t)(b * SDIM + kr1) * EDIM + h * DHDIM + BR * 64 + kc1;
    const int vr0 = s0 >> 2, vc0 = ((s0 & 3) ^ ((vr0 >> 1) & 3)) * 8;
    const int vr1 = s1 >> 2, vc1 = ((s1 & 3) ^ ((vr1 >> 1) & 3)) * 8;
    const u16* vg0 = Vtb + ((size_t)bh * DHDIM + vr0) * SDIM + vc0;
    const u16* vg1 = Vtb + ((size_t)bh * DHDIM + vr1) * SDIM + vc1;
    u16* ksd0 = Ks + s0 * 8; u16* ksd1 = Ks + s1 * 8;
    u16* vsd0 = Vs + s0 * 8; u16* vsd1 = Vs + s1 * 8;

    // prologue: stage iter 0 into buffer 0 (kv 0..63)
    gload16(ksd0, kg0); gload16(ksd1, kg1);
    gload16(vsd0, vg0); gload16(vsd1, vg1);
    gload16(vsd0 + 4096, vg0 + 32); gload16(vsd1 + 4096, vg1 + 32);
    kg0 += 64 * EDIM; kg1 += 64 * EDIM; vg0 += 64; vg1 += 64;

    f32x4 acc[2][8];                    // [qt][dt], one branch
#pragma unroll
    for (int qt = 0; qt < 2; ++qt)
#pragma unroll
        for (int d = 0; d < 8; ++d)
            acc[qt][d] = (f32x4){0.f, 0.f, 0.f, 0.f};
    float lsum[2] = {0.f, 0.f};
    const f32x4 z4 = (f32x4){0.f, 0.f, 0.f, 0.f};

    for (int it = 0; it < 32; ++it) {
        const int cur = it & 1;
        __syncthreads();   // buf[cur] loads complete; all waves done with buf[cur^1]

        if (it < 31) {     // prefetch iter it+1 into the other buffer
            const int kb = (cur ^ 1) * KBUF, vb2 = (cur ^ 1) * VBUF;
            gload16(ksd0 + kb, kg0); gload16(ksd1 + kb, kg1);
            gload16(vsd0 + vb2, vg0); gload16(vsd1 + vb2, vg1);
            gload16(vsd0 + vb2 + 4096, vg0 + 32); gload16(vsd1 + vb2 + 4096, vg1 + 32);
            kg0 += 64 * EDIM; kg1 += 64 * EDIM; vg0 += 64; vg1 += 64;
        }

        const u16* Kc = Ks + cur * KBUF;
        const u16* Vc = Vs + cur * VBUF;

        // ---- batch-load ALL K frags for this iter (8 x ds_read_b128) ----
        bf16x8 kf[4][2];
#pragma unroll
        for (int t2 = 0; t2 < 4; ++t2) {
            const int rb = (t2 * 16 + ln) * 64;
            kf[t2][0] = *(const bf16x8*)&Kc[rb + ((quad ^ lx) * 8)];
            kf[t2][1] = *(const bf16x8*)&Kc[rb + (((4 + quad) ^ lx) * 8)];
        }

        // ---- S^T over 64 kv: st[qt][t2] (MFMAs back-to-back) ----
        f32x4 st[2][4];
#pragma unroll
        for (int t2 = 0; t2 < 4; ++t2)
#pragma unroll
            for (int qt = 0; qt < 2; ++qt) {
                f32x4 s = __builtin_amdgcn_mfma_f32_16x16x32_bf16(kf[t2][0], aq[qt][0], z4, 0, 0, 0);
                st[qt][t2] = __builtin_amdgcn_mfma_f32_16x16x32_bf16(kf[t2][1], aq[qt][1], s, 0, 0, 0);
            }

        // ---- batch-load ALL V frags for this iter (32 x ds_read_b64) ----
        bf16x8 vf[8][2];
#pragma unroll
        for (int dt = 0; dt < 8; ++dt) {
            const int vb = (dt * 16 + ln) * 32;
#pragma unroll
            for (int ks = 0; ks < 2; ++ks) {
                const u16* Vk = Vc + ks * 4096;
                bf16x4 vlo = *(const bf16x4*)&Vk[vb + ((((quad >> 1) + 0) ^ vkey) * 8 + (quad & 1) * 4)];
                bf16x4 vhi = *(const bf16x4*)&Vk[vb + ((((quad >> 1) + 2) ^ vkey) * 8 + (quad & 1) * 4)];
                vf[dt][ks] = __builtin_shufflevector(vlo, vhi, 0, 1, 2, 3, 4, 5, 6, 7);
            }
        }

        // ---- exp + lsum + in-register pack: ap[qt][ks] (ks = kv-32-half) ----
        union { unsigned int u[4]; bf16x8 v; } ap[2][2];
#pragma unroll
        for (int qt = 0; qt < 2; ++qt)
#pragma unroll
            for (int ks = 0; ks < 2; ++ks) {
                float e0 = exp2f(st[qt][2 * ks][0]), e1 = exp2f(st[qt][2 * ks][1]);
                float e2 = exp2f(st[qt][2 * ks][2]), e3 = exp2f(st[qt][2 * ks][3]);
                float f0 = exp2f(st[qt][2 * ks + 1][0]), f1 = exp2f(st[qt][2 * ks + 1][1]);
                float f2 = exp2f(st[qt][2 * ks + 1][2]), f3 = exp2f(st[qt][2 * ks + 1][3]);
                lsum[qt] += (e0 + e1) + (e2 + e3) + (f0 + f1) + (f2 + f3);
                ap[qt][ks].u[0] = __builtin_amdgcn_perm(__float_as_uint(e1), __float_as_uint(e0), 0x07060302u);
                ap[qt][ks].u[1] = __builtin_amdgcn_perm(__float_as_uint(e3), __float_as_uint(e2), 0x07060302u);
                ap[qt][ks].u[2] = __builtin_amdgcn_perm(__float_as_uint(f1), __float_as_uint(f0), 0x07060302u);
                ap[qt][ks].u[3] = __builtin_amdgcn_perm(__float_as_uint(f3), __float_as_uint(f2), 0x07060302u);
            }

        // ---- PV: MFMAs back-to-back from registers ----
#pragma unroll
        for (int dt = 0; dt < 8; ++dt)
#pragma unroll
            for (int ks = 0; ks < 2; ++ks)
#pragma unroll
                for (int qt = 0; qt < 2; ++qt)
                    acc[qt][dt] = __builtin_amdgcn_mfma_f32_16x16x32_bf16(ap[qt][ks].v, vf[dt][ks], acc[qt][dt], 0, 0, 0);
    }

    // ---- epilogue: plain stores (sole writer of branch-BR slots) ----
#pragma unroll
    for (int qt = 0; qt < 2; ++qt) {
#pragma unroll
        for (int r = 0; r < 4; ++r) {
            size_t row = (size_t)(b * SDIM + q0 + qt * 16 + quad * 4 + r);
            float* o = Oacc + ((row * 8 + h) * 2 + BR) * 128 + ln;
#pragma unroll
            for (int dt = 0; dt < 8; ++dt)
                o[dt * 16] = acc[qt][dt][r];
        }
    }
    // ---- l: lane owns q=ln within tile; reduce across quads; store ----
#pragma unroll
    for (int qt = 0; qt < 2; ++qt) {
        float l = lsum[qt];
        l += __shfl_xor(l, 16, 64); l += __shfl_xor(l, 32, 64);
        if (quad == 0)
            Lacc[(size_t)((b * 8 + h) * 2 + BR) * SDIM + q0 + qt * 16 + ln] = l;
    }
}

// ------------------------------------------------------------------
// combine branches + RMSNorm -> bf16 normed. Grid 4096 rows x 256 thr.
// ------------------------------------------------------------------
__global__ __launch_bounds__(256) void rms_combine(
    const float* __restrict__ Oacc, const float* __restrict__ Lacc,
    const float* __restrict__ nw, u16* __restrict__ Nb,
    const float* __restrict__ dwp)
{
    const int row = blockIdx.x;
    const int tid = threadIdx.x;
    const int h = tid >> 5, dh0 = (tid & 31) * 4;
    const int b = row >> 11, q = row & 2047;

    size_t ob = ((size_t)row * 8 + h) * 2 * 128;
    f32x4 a0 = *(const f32x4*)&Oacc[ob + dh0];
    f32x4 a1 = *(const f32x4*)&Oacc[ob + 128 + dh0];
    float l0 = Lacc[(size_t)((b * 8 + h) * 2 + 0) * SDIM + q];
    float l1 = Lacc[(size_t)((b * 8 + h) * 2 + 1) * SDIM + q];
    const float dw = dwp[0];
    float inv0 = 1.0f / l0;
    float inv1 = dw / l1;
    float o[4];
#pragma unroll
    for (int k = 0; k < 4; ++k) o[k] = a0[k] * inv0 - a1[k] * inv1;

    float ss = o[0] * o[0] + o[1] * o[1] + o[2] * o[2] + o[3] * o[3];
    ss += __shfl_xor(ss, 1,  64);
    ss += __shfl_xor(ss, 2,  64);
    ss += __shfl_xor(ss, 4,  64);
    ss += __shfl_xor(ss, 8,  64);
    ss += __shfl_xor(ss, 16, 64);
    ss += __shfl_xor(ss, 32, 64);
    __shared__ float red[4];
    if ((tid & 63) == 0) red[tid >> 6] = ss;
    __syncthreads();
    float tot = red[0] + red[1] + red[2] + red[3];
    float rms = rsqrtf(tot * (1.0f / 1024.0f) + 1.1920929e-07f);

    float4 w = *(const float4*)&nw[tid * 4];
    u16x4 pk;
    pk[0] = bf16rne(o[0] * rms * w.x);
    pk[1] = bf16rne(o[1] * rms * w.y);
    pk[2] = bf16rne(o[2] * rms * w.z);
    pk[3] = bf16rne(o[3] * rms * w.w);
    *(u16x4*)&Nb[(size_t)row * EDIM + tid * 4] = pk;
}

// ------------------------------------------------------------------
extern "C" void kernel_launch(void* const* d_in, const int* in_sizes, int n_in,
                              void* d_out, int out_size, void* d_ws, size_t ws_size,
                              hipStream_t stream)
{
    const float* x   = (const float*)d_in[0];
    const float* Wq  = (const float*)d_in[1];
    const float* Wk  = (const float*)d_in[2];
    const float* Wv  = (const float*)d_in[3];
    const float* nw  = (const float*)d_in[4];
    const float* Wo  = (const float*)d_in[5];
    const float* bo  = (const float*)d_in[6];
    const float* dwp = (const float*)d_in[7];
    float* out = (float*)d_out;

    float* Oacc = (float*)d_ws;                          // 32 MB
    u16*  xb   = (u16*)d_ws;                             // overlays Oacc head
    u16*  wob  = (u16*)((char*)d_ws + 33554432);         // 2 MB
    u16*  wqb  = wob + 1048576;
    u16*  wkb  = wqb + 1048576;
    u16*  wvb  = wkb + 1048576;
    float* Lacc = (float*)wqb;                           // overlays wqb (dead)
    u16*  Qb   = wvb + 1048576;                          // 8 MB
    u16*  Kb   = Qb + 4194304;
    u16*  Vtb  = Kb + 4194304;
    u16*  Nb   = Qb;                                     // overlays Qb (dead)

    cast_bf16<<<4096, 256, 0, stream>>>(x, Wq, Wk, Wv, Wo,
                                        xb, wqb, wkb, wvb, wob);
    gemm_qkv<<<dim3(GN / 128, GM / 128, 3), 256, 0, stream>>>(
        xb, wqb, wkb, wvb, Qb, Kb, Vtb);
    attn_mfma<<<dim3(SDIM / 128, 2 * HDIM, 2), 256, 0, stream>>>(
        Qb, Kb, Vtb, Oacc, Lacc);
    rms_combine<<<4096, 256, 0, stream>>>(Oacc, Lacc, nw, Nb, dwp);
    gemm_out<<<dim3(GN / 128, GM / 128, 1), 256, 0, stream>>>(
        Nb, wob, out, bo, dwp);
}